// Round 6
// baseline (631.631 us; speedup 1.0000x reference)
//
#include <hip/hip_runtime.h>
#include <math.h>

#define DX 192
#define DY 192
#define DZ 128
#define DB 4
#define DXY (DX*DY)              // 36864
#define NTOT ((long)DB*DZ*DY*DX) // 18874368
#define NV ((unsigned)(NTOT/4))  // 4718592 vec4 groups
#define XV (DX/4)                // 48
#define NBLK 1536                // stride = 393216; NV = 12*stride exactly

// ws layout (doubles): [0..12] sum(di*dt), [13..25] sum(dt*dt), [26] bce sum

struct Grp {
    float4 i00, i01, i10, i11, t00, t01, t10, t11;
    float  i00e, i01e, i10e, i11e, t00e, t01e, t10e, t11e;
};

__device__ __forceinline__ void load_grp(Grp& g, const float* __restrict__ ip,
                                         const float* __restrict__ tp,
                                         int oy, int oz, int xe)
{
    g.i00 = *(const float4*)(ip);            g.i00e = ip[xe];
    g.i01 = *(const float4*)(ip + oy);       g.i01e = ip[oy + xe];
    g.i10 = *(const float4*)(ip + oz);       g.i10e = ip[oz + xe];
    g.i11 = *(const float4*)(ip + oz + oy);  g.i11e = ip[oz + oy + xe];
    g.t00 = *(const float4*)(tp);            g.t00e = tp[xe];
    g.t01 = *(const float4*)(tp + oy);       g.t01e = tp[oy + xe];
    g.t10 = *(const float4*)(tp + oz);       g.t10e = tp[oz + xe];
    g.t11 = *(const float4*)(tp + oz + oy);  g.t11e = tp[oz + oy + xe];
}

// corners (z,y,x): c0=(0,0,0) c1=(0,0,1) c2=(0,1,0) c3=(0,1,1)
//                  c4=(1,0,0) c5=(1,0,1) c6=(1,1,0) c7=(1,1,1)
// Clamped loads (oz/oy=0 dupe the row; xe=3 dupes the edge elem) auto-zero the
// three single-axis diffs -> those never need a mask. Diagonal masks only on
// the (rare) boundary path; INTERIOR folds all masks to 1.
template<bool INTERIOR>
__device__ __forceinline__ void compute_grp(const Grp& g, float fz, float fy,
                                            float fx3, float (&A)[27])
{
    const float I0[5] = {g.i00.x, g.i00.y, g.i00.z, g.i00.w, g.i00e};
    const float I1[5] = {g.i01.x, g.i01.y, g.i01.z, g.i01.w, g.i01e};
    const float J0[5] = {g.i10.x, g.i10.y, g.i10.z, g.i10.w, g.i10e};
    const float J1[5] = {g.i11.x, g.i11.y, g.i11.z, g.i11.w, g.i11e};
    const float T0[5] = {g.t00.x, g.t00.y, g.t00.z, g.t00.w, g.t00e};
    const float T1[5] = {g.t01.x, g.t01.y, g.t01.z, g.t01.w, g.t01e};
    const float U0[5] = {g.t10.x, g.t10.y, g.t10.z, g.t10.w, g.t10e};
    const float U1[5] = {g.t11.x, g.t11.y, g.t11.z, g.t11.w, g.t11e};
    const float fzy = fz * fy;

    #pragma unroll
    for (int e = 0; e < 4; ++e) {
        const float fx = (e < 3) ? 1.0f : fx3;   // literal 1 folds for e<3
        float mzy, myx, mzx, mzyx;
        if (INTERIOR) { mzy = 1.f; myx = 1.f; mzx = 1.f; mzyx = 1.f; }
        else { mzy = fzy; myx = fy*fx; mzx = fz*fx; mzyx = fzy*fx; }
        const float c0=I0[e], c1=I0[e+1], c2=I1[e], c3=I1[e+1];
        const float c4=J0[e], c5=J0[e+1], c6=J1[e], c7=J1[e+1];
        const float d0=T0[e], d1=T0[e+1], d2=T1[e], d3=T1[e+1];
        const float d4=U0[e], d5=U0[e+1], d6=U1[e], d7=U1[e+1];
        float di, dt, dtm;
        di=c4-c0; dt=d4-d0;              A[0] +=di*dt;  A[13]+=dt*dt;   // (1,0,0)
        di=c2-c0; dt=d2-d0;              A[1] +=di*dt;  A[14]+=dt*dt;   // (0,1,0)
        di=c1-c0; dt=d1-d0;              A[2] +=di*dt;  A[15]+=dt*dt;   // (0,0,1)
        di=c6-c0; dt=d6-d0; dtm=mzy*dt;  A[3] +=di*dtm; A[16]+=dt*dtm;  // (1,1,0)
        di=c4-c2; dt=d4-d2; dtm=mzy*dt;  A[4] +=di*dtm; A[17]+=dt*dtm;  // (1,-1,0)
        di=c3-c0; dt=d3-d0; dtm=myx*dt;  A[5] +=di*dtm; A[18]+=dt*dtm;  // (0,1,1)
        di=c2-c1; dt=d2-d1; dtm=myx*dt;  A[6] +=di*dtm; A[19]+=dt*dtm;  // (0,1,-1)
        di=c4-c1; dt=d4-d1; dtm=mzx*dt;  A[7] +=di*dtm; A[20]+=dt*dtm;  // (1,0,-1)
        di=c5-c0; dt=d5-d0; dtm=mzx*dt;  A[8] +=di*dtm; A[21]+=dt*dtm;  // (1,0,1)
        di=c4-c3; dt=d4-d3; dtm=mzyx*dt; A[9] +=di*dtm; A[22]+=dt*dtm;  // (1,-1,-1)
        di=c6-c1; dt=d6-d1; dtm=mzyx*dt; A[10]+=di*dtm; A[23]+=dt*dtm;  // (1,1,-1)
        di=c7-c0; dt=d7-d0; dtm=mzyx*dt; A[11]+=di*dtm; A[24]+=dt*dtm;  // (1,1,1)
        di=c5-c2; dt=d5-d2; dtm=mzyx*dt; A[12]+=di*dtm; A[25]+=dt*dtm;  // (1,-1,1)
        float l0 = __logf(c0), l1 = __logf(1.0f - c0);
        A[26] += l1 + d0 * (l0 - l1);
    }
}

__device__ __forceinline__ void prep(unsigned v, const float* __restrict__ inp,
                                     const float* __restrict__ tgt,
                                     const float*& ip, const float*& tp,
                                     int& oy, int& oz, int& xe,
                                     float& fz, float& fy, float& fx3, int& intr)
{
    unsigned xv4 = v % XV;
    unsigned rem = v / XV;
    unsigned y   = rem % DY;
    unsigned z   = (rem / DY) & (DZ - 1);
    ip = inp + (size_t)v * 4;
    tp = tgt + (size_t)v * 4;
    bool by = (y   < DY-1), bz = (z < DZ-1), bx = (xv4 < XV-1);
    oy  = by ? DX  : 0;
    oz  = bz ? DXY : 0;
    xe  = bx ? 4 : 3;
    fy  = by ? 1.f : 0.f;
    fz  = bz ? 1.f : 0.f;
    fx3 = bx ? 1.f : 0.f;
    intr = (by && bz && bx) ? 1 : 0;
}

__global__ __launch_bounds__(256, 4) void gc3d_main(const float* __restrict__ inp,
                                                    const float* __restrict__ tgt,
                                                    double* __restrict__ acc)
{
    float A[27];
    #pragma unroll
    for (int k = 0; k < 27; ++k) A[k] = 0.f;

    unsigned tid = blockIdx.x * 256 + threadIdx.x;
    const unsigned stride = NBLK * 256;

    // NV == 12*stride: every thread runs exactly 6 trips of 2 groups.
    #pragma unroll 1
    for (unsigned v = tid; v < NV; v += 2 * stride) {
        const float *ip1, *tp1, *ip2, *tp2;
        int oy1, oz1, xe1, i1, oy2, oz2, xe2, i2;
        float fz1, fy1, fx1, fz2, fy2, fx2;
        prep(v,          inp, tgt, ip1, tp1, oy1, oz1, xe1, fz1, fy1, fx1, i1);
        prep(v + stride, inp, tgt, ip2, tp2, oy2, oz2, xe2, fz2, fy2, fx2, i2);

        Grp g1, g2;
        load_grp(g1, ip1, tp1, oy1, oz1, xe1);   // 32 independent loads in
        load_grp(g2, ip2, tp2, oy2, oz2, xe2);   // flight before any use

        if (__all(i1)) compute_grp<true >(g1, fz1, fy1, fx1, A);
        else           compute_grp<false>(g1, fz1, fy1, fx1, A);
        if (__all(i2)) compute_grp<true >(g2, fz2, fy2, fx2, A);
        else           compute_grp<false>(g2, fz2, fy2, fx2, A);
    }

    // shuffle tree -> LDS -> 27 double atomics (proven in R1)
    #pragma unroll
    for (int k = 0; k < 27; ++k) {
        #pragma unroll
        for (int o = 32; o > 0; o >>= 1) A[k] += __shfl_down(A[k], o, 64);
    }
    __shared__ float red[4][27];
    int lane = threadIdx.x & 63;
    int wave = threadIdx.x >> 6;
    if (lane == 0) {
        #pragma unroll
        for (int k = 0; k < 27; ++k) red[wave][k] = A[k];
    }
    __syncthreads();
    if (threadIdx.x < 27) {
        float t = red[0][threadIdx.x] + red[1][threadIdx.x]
                + red[2][threadIdx.x] + red[3][threadIdx.x];
        atomicAdd(&acc[threadIdx.x], (double)t);
    }
}

__global__ void gc3d_final(const double* __restrict__ acc, float* __restrict__ out) {
    if (threadIdx.x == 0 && blockIdx.x == 0) {
        double s = 0.0;
        #pragma unroll
        for (int k = 0; k < 13; ++k) s += acc[k] / (acc[13 + k] + 1e-5);
        double bce = -acc[26] / (double)NTOT;
        out[0] = (float)(bce + 1.0 - s / 13.0);
    }
}

extern "C" void kernel_launch(void* const* d_in, const int* in_sizes, int n_in,
                              void* d_out, int out_size, void* d_ws, size_t ws_size,
                              hipStream_t stream) {
    const float* inp = (const float*)d_in[0];
    const float* tgt = (const float*)d_in[1];
    double* acc = (double*)d_ws;

    hipMemsetAsync(d_ws, 0, 27 * sizeof(double), stream);
    gc3d_main<<<NBLK, 256, 0, stream>>>(inp, tgt, acc);
    gc3d_final<<<1, 64, 0, stream>>>(acc, (float*)d_out);
}